// Round 1
// baseline (16815.912 us; speedup 1.0000x reference)
//
#include <hip/hip_runtime.h>
#include <math.h>

namespace {

constexpr int V_  = 32000;
constexpr int K_  = 32;
constexpr int D_  = 256;
constexpr int T_  = 128;
constexpr int B_  = 128;
constexpr int M_  = 16;
constexpr int D4_ = 1024;
constexpr int TD_ = T_ - 1;      // 127
constexpr int R_  = B_ * TD_;    // 16256
constexpr int NCH_ = 32;         // lse column chunks

__device__ __forceinline__ float d_sig(float x){ return 1.0f/(1.0f+__expf(-x)); }
__device__ __forceinline__ float d_tanh(float x){
  float e = __expf(2.0f*x);          // inf-safe: e=inf -> 1, e=0 -> -1
  return 1.0f - 2.0f/(e+1.0f);
}

// ---------------- prep ----------------
__global__ void k_sent_emb(const int* __restrict__ sent, const float* __restrict__ emb,
                           float* __restrict__ out){
  int idx = blockIdx.x*256 + threadIdx.x;     // B*T*D
  int bt = idx >> 8, d = idx & 255;
  out[idx] = emb[(size_t)sent[bt]*D_ + d];
}

__global__ void k_kv_emb(const int* __restrict__ keys, const int* __restrict__ vals,
                         const float* __restrict__ emb, float* __restrict__ kv){
  int idx = blockIdx.x*256 + threadIdx.x;     // B*M*D
  int r = idx >> 8, d = idx & 255;
  kv[idx] = emb[(size_t)keys[r]*D_ + d] + emb[(size_t)vals[r]*D_ + d];
}

__global__ void k_kv_enc(const int* __restrict__ keys, const float* __restrict__ kv,
                         float* __restrict__ out){
  int idx = blockIdx.x*256 + threadIdx.x;     // B*D
  int b = idx >> 8, d = idx & 255;
  float s = 0.0f, c = 0.0f;
  for (int m = 0; m < M_; m++){
    if (keys[b*M_+m] != 0){ s += kv[(size_t)(b*M_+m)*D_ + d]; c += 1.0f; }
  }
  out[idx] = s / c;
}

// C[r][j] = sum_d A[r][d]*W[d][j] + bias[j] ; one block per row
__global__ void k_rowgemm(const float* __restrict__ A, const float* __restrict__ W,
                          const float* __restrict__ bias, float* __restrict__ C,
                          int inner, int cols){
  __shared__ float sA[256];
  int r = blockIdx.x;
  if ((int)threadIdx.x < inner) sA[threadIdx.x] = A[(size_t)r*inner + threadIdx.x];
  __syncthreads();
  for (int j = threadIdx.x; j < cols; j += blockDim.x){
    float acc = bias ? bias[j] : 0.0f;
    #pragma unroll 4
    for (int d = 0; d < inner; d++) acc += sA[d]*W[(size_t)d*cols + j];
    C[(size_t)r*cols + j] = acc;
  }
}

// ---------------- tiled fp32 GEMM: C(rows x cols) = A(rows x 256) @ W(256 x cols) + bias
// FUSED: A[r][k] built on the fly from (zse zeroed at t=0) + sent_emb*wmask, r=b*127+t
template<bool FUSED>
__global__ __launch_bounds__(256) void k_tile_gemm(
    const float* __restrict__ A, const float* __restrict__ W,
    const float* __restrict__ bias, float* __restrict__ C, int cols,
    const float* __restrict__ sent_emb, const float* __restrict__ zse,
    const float* __restrict__ drop, const float* __restrict__ xl){
  __shared__ float As[64*17];
  __shared__ float Ws[16*64];
  int tid = threadIdx.x;
  int tx = tid & 15, ty = tid >> 4;
  int row0 = blockIdx.x*64, col0 = blockIdx.y*64;
  float acc[4][4];
  #pragma unroll
  for (int i=0;i<4;i++) { acc[i][0]=0.f; acc[i][1]=0.f; acc[i][2]=0.f; acc[i][3]=0.f; }
  float xlv = FUSED ? xl[0] : 0.0f;

  for (int k0 = 0; k0 < 256; k0 += 16){
    for (int l = tid; l < 64*16; l += 256){
      int m = l >> 4, kk = l & 15;
      int r = row0 + m, k = k0 + kk;
      float v;
      if (FUSED){
        int b = r / TD_, t = r % TD_;
        int bt = b*T_ + t;
        float wm = (drop[bt] > xlv) ? 1.0f : 0.0f;
        v = sent_emb[(size_t)bt*D_ + k]*wm + (t > 0 ? zse[(size_t)bt*D_ + k] : 0.0f);
      } else {
        v = A[(size_t)r*D_ + k];
      }
      As[m*17 + kk] = v;
    }
    {
      int k = tid >> 4, c4 = (tid & 15)*4;
      *reinterpret_cast<float4*>(&Ws[k*64 + c4]) =
        *reinterpret_cast<const float4*>(&W[(size_t)(k0+k)*cols + col0 + c4]);
    }
    __syncthreads();
    #pragma unroll
    for (int kk = 0; kk < 16; kk++){
      float4 b4 = *reinterpret_cast<const float4*>(&Ws[kk*64 + tx*4]);
      #pragma unroll
      for (int i=0;i<4;i++){
        float a = As[(ty*4+i)*17 + kk];
        acc[i][0] += a*b4.x; acc[i][1] += a*b4.y; acc[i][2] += a*b4.z; acc[i][3] += a*b4.w;
      }
    }
    __syncthreads();
  }
  #pragma unroll
  for (int i=0;i<4;i++){
    int r = row0 + ty*4 + i, c = col0 + tx*4;
    float4 o;
    o.x = acc[i][0] + (bias?bias[c+0]:0.f);
    o.y = acc[i][1] + (bias?bias[c+1]:0.f);
    o.z = acc[i][2] + (bias?bias[c+2]:0.f);
    o.w = acc[i][3] + (bias?bias[c+3]:0.f);
    *reinterpret_cast<float4*>(&C[(size_t)r*cols + c]) = o;
  }
}

// ---------------- encoder LSTM scan (2 batches per block, 512 threads) + fused phi
__global__ __launch_bounds__(512) void k_enc(
    const float* __restrict__ xW, const float* __restrict__ Whh,
    const float* __restrict__ crf_W, const float* __restrict__ crf_b,
    float* __restrict__ phi_raw){
  __shared__ float sh[2][256];
  __shared__ float sred[2][256];
  int tid = threadIdx.x, lb = tid >> 8, lt = tid & 255;
  int b = blockIdx.x*2 + lb;
  float c_reg = 0.0f;
  sh[lb][lt] = 0.0f;
  __syncthreads();
  for (int t = 0; t < T_; t++){
    const float* xr = xW + (size_t)(b*T_ + t)*D4_;
    float a0 = xr[lt], a1 = xr[256+lt], a2 = xr[512+lt], a3 = xr[768+lt];
    #pragma unroll 4
    for (int d = 0; d < 256; d++){
      float hd = sh[lb][d];
      const float* wr = Whh + (size_t)d*D4_ + lt;
      a0 += hd*wr[0]; a1 += hd*wr[256]; a2 += hd*wr[512]; a3 += hd*wr[768];
    }
    float cn = d_sig(a1)*c_reg + d_sig(a0)*d_tanh(a2);
    float hn = d_sig(a3)*d_tanh(cn);
    c_reg = cn;
    __syncthreads();
    sh[lb][lt] = hn;
    __syncthreads();
    {   // phi partials: 8 parts x 32 k
      int k = lt & 31, part = lt >> 5;
      float p = 0.0f;
      #pragma unroll 4
      for (int dd = 0; dd < 32; dd++){
        int d = part*32 + dd;
        p += sh[lb][d] * crf_W[d*K_ + k];
      }
      sred[lb][lt] = p;
    }
    __syncthreads();
    if (lt < K_){
      float p = crf_b[lt];
      #pragma unroll
      for (int q = 0; q < 8; q++) p += sred[lb][q*32 + lt];
      phi_raw[(size_t)t*B_*K_ + b*K_ + lt] = p;
    }
    __syncthreads();
  }
}

__global__ void k_phi_smooth(const float* __restrict__ p, float* __restrict__ o){
  int idx = blockIdx.x*256 + threadIdx.x;   // T*B*K
  int t = idx / (B_*K_);
  float pt = p[idx];
  float v;
  if (t == 0)            v = pt + p[idx + B_*K_];
  else if (t == T_-1)    v = p[idx - B_*K_] + 2.0f*pt;
  else                   v = p[idx - B_*K_] + 2.0f*pt + p[idx + B_*K_];
  o[idx] = v;
}

// ---------------- CRF forward scan + entropy (one block per batch, 1024 thr = 32x32)
__global__ __launch_bounds__(1024) void k_crf(
    const float* __restrict__ phi, const float* __restrict__ trans,
    const int* __restrict__ lens, float* __restrict__ alphas,
    float* __restrict__ ent_b){
  __shared__ float sal[K_], sH[K_];
  int tid = threadIdx.x, b = blockIdx.x;
  int i = tid & 31, j = tid >> 5;
  float tr = trans[i*K_ + j];
  int len = lens[b];
  if (tid < K_){
    float a0 = phi[b*K_ + tid];
    sal[tid] = a0; sH[tid] = 0.0f;
    alphas[b*K_ + tid] = a0;
  }
  __syncthreads();
  for (int t = 1; t < T_; t++){
    bool active = (t < len);
    float ai = sal[i], Hi = sH[i];
    float aj = sal[j], Hj = sH[j];
    float s = ai + tr;
    float m = s;
    #pragma unroll
    for (int off=16; off; off>>=1) m = fmaxf(m, __shfl_xor(m, off, 32));
    float e = expf(s - m);
    float E = e;
    #pragma unroll
    for (int off=16; off; off>>=1) E += __shfl_xor(E, off, 32);
    float lZ = m + logf(E);
    float w = e / E;
    float logw = s - lZ;
    float nH = w * (Hi - logw);
    #pragma unroll
    for (int off=16; off; off>>=1) nH += __shfl_xor(nH, off, 32);
    float na = lZ + phi[(size_t)t*B_*K_ + b*K_ + j];
    float outa = active ? na : aj;
    float outH = active ? nH : Hj;
    __syncthreads();
    if (i == 0){
      sal[j] = outa; sH[j] = outH;
      alphas[(size_t)t*B_*K_ + b*K_ + j] = outa;
    }
    __syncthreads();
  }
  if (tid < K_){
    float a = sal[tid];
    float m = a;
    #pragma unroll
    for (int off=16; off; off>>=1) m = fmaxf(m, __shfl_xor(m, off, 32));
    float e = expf(a-m), E = e;
    #pragma unroll
    for (int off=16; off; off>>=1) E += __shfl_xor(E, off, 32);
    float lse = m + logf(E);
    float lp = a - lse;
    float v = expf(lp)*(sH[tid]-lp);
    #pragma unroll
    for (int off=16; off; off>>=1) v += __shfl_xor(v, off, 32);
    if (tid == 0) ent_b[b] = v;
  }
}

// ---------------- backward Gumbel sampler (one block per batch)
__global__ void k_sampler(const float* __restrict__ alphas, const float* __restrict__ trans,
                          const float* __restrict__ gum, const int* __restrict__ lens,
                          const float* __restrict__ tau_p,
                          float* __restrict__ y_all, int* __restrict__ z_ids){
  int b = blockIdx.x;
  int lane = threadIdx.x;       // 64
  int k = lane & 31;
  float inv_tau = 1.0f / tau_p[0];
  int len = lens[b];
  int nid = 0;
  for (int t = T_-1; t >= 0; t--){
    bool active  = (t < len);
    bool is_last = (t == len-1);
    float a = alphas[(size_t)t*B_*K_ + b*K_ + k];
    float lg = is_last ? a : a + trans[k*K_ + nid];
    float val = (lg + gum[(size_t)t*B_*K_ + b*K_ + k]) * inv_tau;
    float m = val;
    #pragma unroll
    for (int off=16; off; off>>=1) m = fmaxf(m, __shfl_xor(m, off, 32));
    float e = expf(val - m), E = e;
    #pragma unroll
    for (int off=16; off; off>>=1) E += __shfl_xor(E, off, 32);
    float y = active ? e/E : 0.0f;
    if (lane < K_) y_all[(size_t)(b*T_ + t)*K_ + k] = y;
    float bv = val; int bk = k;
    #pragma unroll
    for (int off=16; off; off>>=1){
      float ov = __shfl_xor(bv, off, 32);
      int   ok = __shfl_xor(bk, off, 32);
      if (ov > bv || (ov == bv && ok < bk)){ bv = ov; bk = ok; }
    }
    int ids = active ? bk : 0;
    nid = ids;
    if (lane == 0) z_ids[b*T_ + t] = ids;
  }
}

// ---------------- decoder scan (2 batches per block, 512 threads)
__global__ __launch_bounds__(512) void k_dec(
    const float* __restrict__ xW, const float* __restrict__ Whh,
    const float* __restrict__ h0, const float* __restrict__ c0,
    const float* __restrict__ memk, const float* __restrict__ memk2,
    const float* __restrict__ kv_emb, const int* __restrict__ keys,
    const float* __restrict__ av, const float* __restrict__ cv,
    const float* __restrict__ aoW, const float* __restrict__ aob,
    const float* __restrict__ pzW, const float* __restrict__ pzb,
    const float* __restrict__ iW, const float* __restrict__ ib,
    const float* __restrict__ cWq, const float* __restrict__ Wq,
    const float* __restrict__ gW, const float* __restrict__ gb,
    const float* __restrict__ zse, const int* __restrict__ sent,
    const int* __restrict__ zids,
    float* __restrict__ dec_int_g, float* __restrict__ lpz_g,
    float* __restrict__ gsig_g, float* __restrict__ cpx_g){
  __shared__ float sh[2][256], sq[2][256], sdo[2][256], sdi[2][256], sctx[2][256], szn[2][256];
  __shared__ float se[2][16], se2[2][16], szl[2][32], sred[2][8];
  int tid = threadIdx.x, lb = tid >> 8, lt = tid & 255;
  int b = blockIdx.x*2 + lb;
  float c_reg = c0[b*256 + lt];
  sh[lb][lt] = h0[b*256 + lt];
  __syncthreads();
  for (int t = 0; t < TD_; t++){
    int r = b*TD_ + t;
    // 1. LSTM
    const float* xr = xW + (size_t)r*D4_;
    float a0 = xr[lt], a1 = xr[256+lt], a2 = xr[512+lt], a3 = xr[768+lt];
    #pragma unroll 4
    for (int d = 0; d < 256; d++){
      float hd = sh[lb][d];
      const float* wr = Whh + (size_t)d*D4_ + lt;
      a0 += hd*wr[0]; a1 += hd*wr[256]; a2 += hd*wr[512]; a3 += hd*wr[768];
    }
    float cn = d_sig(a1)*c_reg + d_sig(a0)*d_tanh(a2);
    float hn = d_sig(a3)*d_tanh(cn);
    c_reg = cn;
    __syncthreads();
    sh[lb][lt] = hn;
    szn[lb][lt] = zse[(size_t)(b*T_ + t + 1)*256 + lt];
    __syncthreads();
    // 2. q = h @ attn_Wq
    {
      float acc = 0.0f;
      #pragma unroll 4
      for (int d = 0; d < 256; d++) acc += sh[lb][d]*Wq[(size_t)d*256 + lt];
      sq[lb][lt] = acc;
    }
    __syncthreads();
    // 3. e[m]
    {
      int m = lt >> 4, ds = lt & 15;
      float p = 0.0f;
      #pragma unroll 4
      for (int qq = 0; qq < 16; qq++){
        int d = ds + qq*16;
        p += d_tanh(sq[lb][d] + memk[(size_t)(b*M_+m)*256 + d]) * av[d];
      }
      #pragma unroll
      for (int off=8; off; off>>=1) p += __shfl_xor(p, off, 16);
      if (ds == 0) se[lb][m] = (keys[b*M_+m] != 0) ? p : -1e9f;
    }
    __syncthreads();
    // 4. softmax over m, ctx
    {
      float mx = -1e30f;
      #pragma unroll
      for (int m=0;m<16;m++) mx = fmaxf(mx, se[lb][m]);
      float den = 0.0f; float ex[16];
      #pragma unroll
      for (int m=0;m<16;m++){ ex[m] = __expf(se[lb][m]-mx); den += ex[m]; }
      float ctx = 0.0f;
      #pragma unroll
      for (int m=0;m<16;m++) ctx += ex[m] * kv_emb[(size_t)(b*M_+m)*256 + lt];
      sctx[lb][lt] = ctx/den;
    }
    __syncthreads();
    // 5. dec_out
    {
      float acc = aob[lt];
      #pragma unroll 4
      for (int d = 0; d < 256; d++){
        acc += sh[lb][d]  * aoW[(size_t)d*256 + lt];
        acc += sctx[lb][d]* aoW[(size_t)(256+d)*256 + lt];
      }
      sdo[lb][lt] = acc;
    }
    __syncthreads();
    // 6. z_logits (lanes<32) + 7. dec_int
    if (lt < 32){
      float acc = pzb[lt];
      #pragma unroll 4
      for (int d = 0; d < 256; d++) acc += sdo[lb][d]*pzW[d*K_ + lt];
      szl[lb][lt] = acc;
    }
    {
      float acc = ib[lt];
      #pragma unroll 4
      for (int d = 0; d < 256; d++){
        acc += sdo[lb][d]*iW[(size_t)d*256 + lt];
        acc += szn[lb][d]*iW[(size_t)(256+d)*256 + lt];
      }
      sdi[lb][lt] = acc;
      dec_int_g[(size_t)r*256 + lt] = acc;
    }
    __syncthreads();
    // 8. lpz
    if (lt < 32){
      float zl = szl[lb][lt];
      float m = zl;
      #pragma unroll
      for (int off=16; off; off>>=1) m = fmaxf(m, __shfl_xor(m, off, 32));
      float e = __expf(zl-m), E = e;
      #pragma unroll
      for (int off=16; off; off>>=1) E += __shfl_xor(E, off, 32);
      if (lt == 0){
        int tz = zids[b*T_ + t + 1];
        lpz_g[r] = szl[lb][tz] - (m + logf(E));
      }
    }
    // 9. q2 = dec_int @ cattn_Wq (reuse sq)
    {
      float acc = 0.0f;
      #pragma unroll 4
      for (int d = 0; d < 256; d++) acc += sdi[lb][d]*cWq[(size_t)d*256 + lt];
      sq[lb][lt] = acc;
    }
    __syncthreads();
    // 10. e2
    {
      int m = lt >> 4, ds = lt & 15;
      float p = 0.0f;
      #pragma unroll 4
      for (int qq = 0; qq < 16; qq++){
        int d = ds + qq*16;
        p += d_tanh(sq[lb][d] + memk2[(size_t)(b*M_+m)*256 + d]) * cv[d];
      }
      #pragma unroll
      for (int off=8; off; off>>=1) p += __shfl_xor(p, off, 16);
      if (ds == 0) se2[lb][m] = (keys[b*M_+m] != 0) ? p : -1e9f;
    }
    // 11. g partial
    {
      float gp = sdi[lb][lt]*gW[lt];
      #pragma unroll
      for (int off=32; off; off>>=1) gp += __shfl_xor(gp, off, 64);
      if ((tid & 63) == 0) sred[lb][lt>>6] = gp;
    }
    __syncthreads();
    if (lt == 0){
      float mx = -1e30f;
      #pragma unroll
      for (int m=0;m<16;m++) mx = fmaxf(mx, se2[lb][m]);
      float den = 0.0f; float ex[16];
      #pragma unroll
      for (int m=0;m<16;m++){ ex[m] = __expf(se2[lb][m]-mx); den += ex[m]; }
      int tx = sent[b*T_ + t + 1];
      float cpx = 0.0f;
      #pragma unroll
      for (int m=0;m<16;m++) if (keys[b*M_+m] == tx) cpx += ex[m]/den;
      cpx_g[r] = cpx;
      float gs = sred[lb][0]+sred[lb][1]+sred[lb][2]+sred[lb][3] + gb[0];
      gsig_g[r] = d_sig(gs);
    }
    __syncthreads();
  }
}

// ---------------- big fused GEMM + online logsumexp over V (fp32)
__global__ __launch_bounds__(256) void k_lse_gemm(
    const float* __restrict__ A,      // dec_int R_ x 256
    const float* __restrict__ W,      // out_W 256 x V
    const float* __restrict__ bias,   // out_b
    float* __restrict__ part){        // R_ x NCH_ x 2 (m,s)
  __shared__ float sA[64*257];
  __shared__ float sW[16*64];
  int tid = threadIdx.x, tx = tid & 15, ty = tid >> 4;
  int row0 = blockIdx.x * 64;
  for (int l = tid; l < 64*256; l += 256){
    int m = l >> 8, k = l & 255;
    sA[m*257 + k] = A[(size_t)(row0+m)*256 + k];
  }
  __syncthreads();
  float rm[4], rs[4];
  #pragma unroll
  for (int i=0;i<4;i++){ rm[i] = -3.0e38f; rs[i] = 0.0f; }
  for (int ct = blockIdx.y; ct < 500; ct += NCH_){
    int col0 = ct*64;
    float acc[4][4];
    #pragma unroll
    for (int i=0;i<4;i++){ acc[i][0]=0.f; acc[i][1]=0.f; acc[i][2]=0.f; acc[i][3]=0.f; }
    for (int k0 = 0; k0 < 256; k0 += 16){
      __syncthreads();
      {
        int k = tid >> 4, c4 = (tid & 15)*4;
        *reinterpret_cast<float4*>(&sW[k*64 + c4]) =
          *reinterpret_cast<const float4*>(&W[(size_t)(k0+k)*V_ + col0 + c4]);
      }
      __syncthreads();
      #pragma unroll
      for (int kk = 0; kk < 16; kk++){
        float4 b4 = *reinterpret_cast<const float4*>(&sW[kk*64 + tx*4]);
        #pragma unroll
        for (int i=0;i<4;i++){
          float a = sA[(ty*4+i)*257 + k0 + kk];
          acc[i][0] += a*b4.x; acc[i][1] += a*b4.y; acc[i][2] += a*b4.z; acc[i][3] += a*b4.w;
        }
      }
    }
    float bx = bias[col0+tx*4], by = bias[col0+tx*4+1], bz = bias[col0+tx*4+2], bw = bias[col0+tx*4+3];
    #pragma unroll
    for (int i=0;i<4;i++){
      float v0=acc[i][0]+bx, v1=acc[i][1]+by, v2=acc[i][2]+bz, v3=acc[i][3]+bw;
      float tm = fmaxf(fmaxf(v0,v1), fmaxf(v2,v3));
      #pragma unroll
      for (int off=8; off; off>>=1) tm = fmaxf(tm, __shfl_xor(tm, off, 16));
      float ts = __expf(v0-tm)+__expf(v1-tm)+__expf(v2-tm)+__expf(v3-tm);
      #pragma unroll
      for (int off=8; off; off>>=1) ts += __shfl_xor(ts, off, 16);
      if (tx == 0){
        float M = fmaxf(rm[i], tm);
        rs[i] = rs[i]*__expf(rm[i]-M) + ts*__expf(tm-M);
        rm[i] = M;
      }
    }
  }
  if (tx == 0){
    #pragma unroll
    for (int i=0;i<4;i++){
      int r = row0 + ty*4 + i;
      part[((size_t)r*NCH_ + blockIdx.y)*2 + 0] = rm[i];
      part[((size_t)r*NCH_ + blockIdx.y)*2 + 1] = rs[i];
    }
  }
}

__global__ void k_lse_combine(const float* __restrict__ part, float* __restrict__ lse){
  int r = blockIdx.x*256 + threadIdx.x;
  if (r >= R_) return;
  float M = -3.0e38f;
  for (int c = 0; c < NCH_; c++) M = fmaxf(M, part[((size_t)r*NCH_+c)*2]);
  float S = 0.0f;
  for (int c = 0; c < NCH_; c++){
    float m = part[((size_t)r*NCH_+c)*2], s = part[((size_t)r*NCH_+c)*2+1];
    S += s*__expf(m - M);
  }
  lse[r] = M + logf(S);
}

__global__ void k_logit_tx(const float* __restrict__ dint, const float* __restrict__ W,
                           const float* __restrict__ bias, const int* __restrict__ sent,
                           float* __restrict__ out){
  int r = blockIdx.x;
  int b = r / TD_, t = r % TD_;
  int tx = sent[b*T_ + t + 1];
  int lane = threadIdx.x;
  float acc = 0.0f;
  #pragma unroll
  for (int q = 0; q < 4; q++){
    int d = lane + q*64;
    acc += dint[(size_t)r*256 + d]*W[(size_t)d*V_ + tx];
  }
  #pragma unroll
  for (int off=32; off; off>>=1) acc += __shfl_xor(acc, off, 64);
  if (lane == 0) out[r] = acc + bias[tx];
}

__global__ __launch_bounds__(256) void k_final(
    const float* __restrict__ lse, const float* __restrict__ ltx,
    const float* __restrict__ gsig, const float* __restrict__ cpx,
    const float* __restrict__ lpz, const float* __restrict__ ent_b,
    const int* __restrict__ lens, float* __restrict__ out){
  __shared__ float sred[256];
  int tid = threadIdx.x;
  float sum = 0.0f;
  for (int r = tid; r < R_; r += 256){
    int b = r / TD_, t = r % TD_;
    if (t < lens[b]){
      float g = gsig[r];
      float lm = __expf(ltx[r] - lse[r]);
      float p = (1.0f-g)*lm + g*cpx[r] + 1e-10f;
      sum += logf(p) + lpz[r];
    }
  }
  sred[tid] = sum;
  __syncthreads();
  for (int s = 128; s; s >>= 1){ if (tid < s) sred[tid] += sred[tid+s]; __syncthreads(); }
  if (tid == 0){
    float es = 0.0f, dn = 0.0f;
    for (int b = 0; b < B_; b++){ es += ent_b[b]; dn += (float)lens[b]; }
    out[0] = -( es/(float)B_ + sred[0]/dn );
  }
}

} // anonymous namespace

extern "C" void kernel_launch(void* const* d_in, const int* in_sizes, int n_in,
                              void* d_out, int out_size, void* d_ws, size_t ws_size,
                              hipStream_t stream){
  const int*   keys  = (const int*)d_in[0];
  const int*   vals  = (const int*)d_in[1];
  const int*   sent  = (const int*)d_in[2];
  const int*   lens  = (const int*)d_in[3];
  const float* tau   = (const float*)d_in[4];
  const float* xl    = (const float*)d_in[5];
  const float* gum   = (const float*)d_in[6];
  const float* drop  = (const float*)d_in[7];
  const float* emb   = (const float*)d_in[8];
  const float* z_emb = (const float*)d_in[9];
  const float* eWih  = (const float*)d_in[10];
  const float* eWhh  = (const float*)d_in[11];
  const float* eb    = (const float*)d_in[12];
  const float* crfW  = (const float*)d_in[13];
  const float* crfb  = (const float*)d_in[14];
  const float* trans = (const float*)d_in[15];
  const float* iWh   = (const float*)d_in[16];
  const float* ibh   = (const float*)d_in[17];
  const float* iWc   = (const float*)d_in[18];
  const float* ibc   = (const float*)d_in[19];
  const float* dWih  = (const float*)d_in[20];
  const float* dWhh  = (const float*)d_in[21];
  const float* db    = (const float*)d_in[22];
  const float* aWq   = (const float*)d_in[23];
  const float* aWk   = (const float*)d_in[24];
  const float* av    = (const float*)d_in[25];
  const float* aoW   = (const float*)d_in[26];
  const float* aob   = (const float*)d_in[27];
  const float* pzW   = (const float*)d_in[28];
  const float* pzb   = (const float*)d_in[29];
  const float* intW  = (const float*)d_in[30];
  const float* intb  = (const float*)d_in[31];
  const float* outW  = (const float*)d_in[32];
  const float* outb  = (const float*)d_in[33];
  const float* cWq   = (const float*)d_in[34];
  const float* cWk   = (const float*)d_in[35];
  const float* cv    = (const float*)d_in[36];
  const float* gW    = (const float*)d_in[37];
  const float* gb    = (const float*)d_in[38];
  (void)in_sizes; (void)n_in; (void)out_size; (void)ws_size;

  float* ws = (float*)d_ws;
  size_t o = 0;
  auto alloc = [&](size_t n){ size_t r = o; o += n; return r; };
  float* sent_emb = ws + alloc((size_t)B_*T_*D_);
  float* kv_emb   = ws + alloc((size_t)B_*M_*D_);
  float* kv_enc   = ws + alloc((size_t)B_*D_);
  float* h0       = ws + alloc((size_t)B_*D_);
  float* c0       = ws + alloc((size_t)B_*D_);
  float* memk     = ws + alloc((size_t)B_*M_*D_);
  float* memk2    = ws + alloc((size_t)B_*M_*D_);
  float* xW       = ws + alloc((size_t)B_*T_*D4_);    // reused for enc then dec
  float* phi_raw  = ws + alloc((size_t)T_*B_*K_);
  float* phi_sm   = ws + alloc((size_t)T_*B_*K_);
  float* alphas   = ws + alloc((size_t)T_*B_*K_);
  float* ent_b    = ws + alloc((size_t)B_);
  float* y_all    = ws + alloc((size_t)B_*T_*K_);
  float* zse      = ws + alloc((size_t)B_*T_*D_);
  float* dec_int  = ws + alloc((size_t)R_*D_);
  float* lpz_b    = ws + alloc((size_t)R_);
  float* gsig     = ws + alloc((size_t)R_);
  float* cpx      = ws + alloc((size_t)R_);
  float* ltx      = ws + alloc((size_t)R_);
  float* part     = ws + alloc((size_t)R_*NCH_*2);
  float* lse      = ws + alloc((size_t)R_);
  int*   z_ids    = (int*)(ws + alloc((size_t)B_*T_));

  k_sent_emb<<<B_*T_*D_/256, 256, 0, stream>>>(sent, emb, sent_emb);
  k_kv_emb  <<<B_*M_*D_/256, 256, 0, stream>>>(keys, vals, emb, kv_emb);
  k_kv_enc  <<<B_*D_/256, 256, 0, stream>>>(keys, kv_emb, kv_enc);
  k_rowgemm <<<B_,     256, 0, stream>>>(kv_enc, iWh, ibh, h0, 256, 256);
  k_rowgemm <<<B_,     256, 0, stream>>>(kv_enc, iWc, ibc, c0, 256, 256);
  k_rowgemm <<<B_*M_,  256, 0, stream>>>(kv_emb, aWk, nullptr, memk, 256, 256);
  k_rowgemm <<<B_*M_,  256, 0, stream>>>(kv_emb, cWk, nullptr, memk2, 256, 256);
  k_tile_gemm<false><<<dim3(B_*T_/64, D4_/64), 256, 0, stream>>>(
      sent_emb, eWih, eb, xW, D4_, nullptr, nullptr, nullptr, nullptr);
  k_enc<<<B_/2, 512, 0, stream>>>(xW, eWhh, crfW, crfb, phi_raw);
  k_phi_smooth<<<T_*B_*K_/256, 256, 0, stream>>>(phi_raw, phi_sm);
  k_crf<<<B_, 1024, 0, stream>>>(phi_sm, trans, lens, alphas, ent_b);
  k_sampler<<<B_, 64, 0, stream>>>(alphas, trans, gum, lens, tau, y_all, z_ids);
  k_rowgemm<<<B_*T_, 256, 0, stream>>>(y_all, z_emb, nullptr, zse, K_, 256);
  k_tile_gemm<true><<<dim3(R_/64, D4_/64), 256, 0, stream>>>(
      nullptr, dWih, db, xW, D4_, sent_emb, zse, drop, xl);
  k_dec<<<B_/2, 512, 0, stream>>>(xW, dWhh, h0, c0, memk, memk2, kv_emb, keys,
                                  av, cv, aoW, aob, pzW, pzb, intW, intb,
                                  cWq, aWq, gW, gb, zse, sent, z_ids,
                                  dec_int, lpz_b, gsig, cpx);
  k_lse_gemm<<<dim3(R_/64, NCH_), 256, 0, stream>>>(dec_int, outW, outb, part);
  k_lse_combine<<<(R_+255)/256, 256, 0, stream>>>(part, lse);
  k_logit_tx<<<R_, 64, 0, stream>>>(dec_int, outW, outb, sent, ltx);
  k_final<<<1, 256, 0, stream>>>(lse, ltx, gsig, cpx, lpz_b, ent_b, lens, (float*)d_out);
}

// Round 2
// 4557.707 us; speedup vs baseline: 3.6896x; 3.6896x over previous
//
#include <hip/hip_runtime.h>
#include <math.h>

namespace {

constexpr int V_  = 32000;
constexpr int K_  = 32;
constexpr int D_  = 256;
constexpr int T_  = 128;
constexpr int B_  = 128;
constexpr int M_  = 16;
constexpr int D4_ = 1024;
constexpr int TD_ = T_ - 1;      // 127
constexpr int R_  = B_ * TD_;    // 16256
constexpr int NCH_ = 32;         // lse column chunks

typedef __attribute__((ext_vector_type(8))) short short8;
typedef __attribute__((ext_vector_type(4))) float f32x4;

__device__ __forceinline__ float d_sig(float x){ return 1.0f/(1.0f+__expf(-x)); }
__device__ __forceinline__ float d_tanh(float x){
  float e = __expf(2.0f*x);          // inf-safe
  return 1.0f - 2.0f/(e+1.0f);
}
__device__ __forceinline__ unsigned short f2bf(float f){  // RNE fp32->bf16
  unsigned int x = __float_as_uint(f);
  unsigned int r = (x + 0x7FFFu + ((x>>16)&1u)) >> 16;
  return (unsigned short)r;
}

// ---------------- prep ----------------
__global__ void k_sent_emb(const int* __restrict__ sent, const float* __restrict__ emb,
                           float* __restrict__ out){
  int idx = blockIdx.x*256 + threadIdx.x;     // B*T*D
  int bt = idx >> 8, d = idx & 255;
  out[idx] = emb[(size_t)sent[bt]*D_ + d];
}

__global__ void k_kv_emb(const int* __restrict__ keys, const int* __restrict__ vals,
                         const float* __restrict__ emb, float* __restrict__ kv){
  int idx = blockIdx.x*256 + threadIdx.x;     // B*M*D
  int r = idx >> 8, d = idx & 255;
  kv[idx] = emb[(size_t)keys[r]*D_ + d] + emb[(size_t)vals[r]*D_ + d];
}

__global__ void k_kv_enc(const int* __restrict__ keys, const float* __restrict__ kv,
                         float* __restrict__ out){
  int idx = blockIdx.x*256 + threadIdx.x;     // B*D
  int b = idx >> 8, d = idx & 255;
  float s = 0.0f, c = 0.0f;
  for (int m = 0; m < M_; m++){
    if (keys[b*M_+m] != 0){ s += kv[(size_t)(b*M_+m)*D_ + d]; c += 1.0f; }
  }
  out[idx] = s / c;
}

// one block per row: C[r][j] = sum_d A[r][d]*W[d][j] + bias
__global__ void k_rowgemm(const float* __restrict__ A, const float* __restrict__ W,
                          const float* __restrict__ bias, float* __restrict__ C,
                          int inner, int cols){
  __shared__ float sA[256];
  int r = blockIdx.x;
  if ((int)threadIdx.x < inner) sA[threadIdx.x] = A[(size_t)r*inner + threadIdx.x];
  __syncthreads();
  for (int j = threadIdx.x; j < cols; j += blockDim.x){
    float acc = bias ? bias[j] : 0.0f;
    #pragma unroll 4
    for (int d = 0; d < inner; d++) acc += sA[d]*W[(size_t)d*cols + j];
    C[(size_t)r*cols + j] = acc;
  }
}

// ---------------- tiled fp32 GEMM, A gathered by MODE
// MODE 0: A1[r][k], lda=INNER
// MODE 1: dec-inputs fused: (sent_emb*wmask + (t>0)*zse)[bt][k]   (INNER=256)
// MODE 2: concat [A1 | A2], both R x 256                          (INNER=512)
// MODE 3: concat [A1 | zse[b*T+t+1]]                              (INNER=512)
template<int INNER, int MODE>
__global__ __launch_bounds__(256) void k_tile_gemm(
    const float* __restrict__ A1, const float* __restrict__ A2,
    const float* __restrict__ W, const float* __restrict__ bias,
    float* __restrict__ C, int cols,
    const float* __restrict__ drop, const float* __restrict__ xl){
  __shared__ float As[64*17];
  __shared__ float Ws[16*64];
  int tid = threadIdx.x;
  int tx = tid & 15, ty = tid >> 4;
  int row0 = blockIdx.x*64, col0 = blockIdx.y*64;
  float acc[4][4];
  #pragma unroll
  for (int i=0;i<4;i++){ acc[i][0]=0.f; acc[i][1]=0.f; acc[i][2]=0.f; acc[i][3]=0.f; }
  float xlv = 0.0f;
  if constexpr (MODE==1) xlv = xl[0];

  for (int k0 = 0; k0 < INNER; k0 += 16){
    for (int l = tid; l < 64*16; l += 256){
      int m = l >> 4, kk = l & 15;
      int r = row0 + m, k = k0 + kk;
      float v;
      if constexpr (MODE==0){
        v = A1[(size_t)r*INNER + k];
      } else if constexpr (MODE==1){
        int b = r / TD_, t = r - b*TD_;
        int bt = b*T_ + t;
        float wm = (drop[bt] > xlv) ? 1.0f : 0.0f;
        v = A1[(size_t)bt*D_ + k]*wm + (t > 0 ? A2[(size_t)bt*D_ + k] : 0.0f);
      } else if constexpr (MODE==2){
        v = (k < 256) ? A1[(size_t)r*256 + k] : A2[(size_t)r*256 + (k-256)];
      } else {
        if (k < 256) v = A1[(size_t)r*256 + k];
        else { int b = r / TD_, t = r - b*TD_; v = A2[(size_t)(b*T_ + t + 1)*256 + (k-256)]; }
      }
      As[m*17 + kk] = v;
    }
    {
      int k = tid >> 4, c4 = (tid & 15)*4;
      *reinterpret_cast<float4*>(&Ws[k*64 + c4]) =
        *reinterpret_cast<const float4*>(&W[(size_t)(k0+k)*cols + col0 + c4]);
    }
    __syncthreads();
    #pragma unroll
    for (int kk = 0; kk < 16; kk++){
      float4 b4 = *reinterpret_cast<const float4*>(&Ws[kk*64 + tx*4]);
      #pragma unroll
      for (int i=0;i<4;i++){
        float a = As[(ty*4+i)*17 + kk];
        acc[i][0] += a*b4.x; acc[i][1] += a*b4.y; acc[i][2] += a*b4.z; acc[i][3] += a*b4.w;
      }
    }
    __syncthreads();
  }
  #pragma unroll
  for (int i=0;i<4;i++){
    int r = row0 + ty*4 + i, c = col0 + tx*4;
    float4 o;
    o.x = acc[i][0] + (bias?bias[c+0]:0.f);
    o.y = acc[i][1] + (bias?bias[c+1]:0.f);
    o.z = acc[i][2] + (bias?bias[c+2]:0.f);
    o.w = acc[i][3] + (bias?bias[c+3]:0.f);
    *reinterpret_cast<float4*>(&C[(size_t)r*cols + c]) = o;
  }
}

// ---------------- LSTM-only scan: 2 batches/block, 512 threads
// thread tid owns gate cols {tid, tid+512} for both batches
__global__ __launch_bounds__(512) void k_lstm_scan(
    const float* __restrict__ xW,   // [B][NT][1024]
    const float* __restrict__ Whh,  // [256][1024]
    const float* __restrict__ h0, const float* __restrict__ c0,
    float* __restrict__ Hout, int NT){
  __shared__ float h2[256][2];
  __shared__ float g2[1024][2];
  int tid = threadIdx.x;
  int b0 = blockIdx.x*2;
  int lb = tid >> 8, d = tid & 255;
  float c_reg = c0 ? c0[(b0+lb)*256 + d] : 0.0f;
  if (tid < 256){
    h2[tid][0] = h0 ? h0[(size_t)b0*256 + tid]     : 0.0f;
    h2[tid][1] = h0 ? h0[(size_t)(b0+1)*256 + tid] : 0.0f;
  }
  __syncthreads();
  const int col0 = tid, col1 = tid + 512;
  for (int t = 0; t < NT; t++){
    const float* x0 = xW + ((size_t)b0*NT + t)*D4_;
    const float* x1 = xW + ((size_t)(b0+1)*NT + t)*D4_;
    float a0x = x0[col0], a0y = x1[col0];
    float a1x = x0[col1], a1y = x1[col1];
    #pragma unroll 8
    for (int dd = 0; dd < 256; dd++){
      float hx = h2[dd][0], hy = h2[dd][1];
      float w0 = Whh[(size_t)dd*D4_ + col0];
      float w1 = Whh[(size_t)dd*D4_ + col1];
      a0x += w0*hx; a0y += w0*hy;
      a1x += w1*hx; a1y += w1*hy;
    }
    __syncthreads();
    g2[col0][0] = a0x; g2[col0][1] = a0y;
    g2[col1][0] = a1x; g2[col1][1] = a1y;
    __syncthreads();
    float gi = g2[d][lb], gf = g2[256+d][lb], gg = g2[512+d][lb], go = g2[768+d][lb];
    float cn = d_sig(gf)*c_reg + d_sig(gi)*d_tanh(gg);
    float hn = d_sig(go)*d_tanh(cn);
    c_reg = cn;
    h2[d][lb] = hn;
    Hout[((size_t)(b0+lb)*NT + t)*D_ + d] = hn;
    __syncthreads();
  }
}

// ---------------- phi = enc_out @ crf_W + b  (writes time-major [t][b][k])
__global__ __launch_bounds__(256) void k_phi(const float* __restrict__ H,
    const float* __restrict__ Wc, const float* __restrict__ bc,
    float* __restrict__ phi){
  int tid = threadIdx.x; int rl = tid >> 5, j = tid & 31;
  int r = blockIdx.x*8 + rl;          // r = b*128 + t
  int b = r >> 7, t = r & 127;
  float acc = bc[j];
  #pragma unroll 4
  for (int d = 0; d < 256; d++) acc += H[(size_t)r*256 + d]*Wc[d*K_ + j];
  phi[(size_t)t*B_*K_ + b*K_ + j] = acc;
}

// ---------------- z_logits = dec_out @ pzW + pzb  ([r][32])
__global__ __launch_bounds__(256) void k_zl(const float* __restrict__ A,
    const float* __restrict__ Wz, const float* __restrict__ bz,
    float* __restrict__ zl){
  int tid = threadIdx.x; int rl = tid >> 5, j = tid & 31;
  int r = blockIdx.x*8 + rl;
  float acc = bz[j];
  #pragma unroll 4
  for (int d = 0; d < 256; d++) acc += A[(size_t)r*256 + d]*Wz[d*K_ + j];
  zl[(size_t)r*K_ + j] = acc;
}

__global__ void k_lpz(const float* __restrict__ zl, const int* __restrict__ zids,
                      float* __restrict__ lpz){
  int r = blockIdx.x; int lane = threadIdx.x;
  if (lane >= 32) return;
  float v = zl[(size_t)r*K_ + lane];
  float m = v;
  #pragma unroll
  for (int off=16; off; off>>=1) m = fmaxf(m, __shfl_xor(m, off, 32));
  float e = __expf(v-m), E = e;
  #pragma unroll
  for (int off=16; off; off>>=1) E += __shfl_xor(E, off, 32);
  if (lane == 0){
    int b = r / TD_, t = r - b*TD_;
    int tz = zids[b*T_ + t + 1];
    lpz[r] = zl[(size_t)r*K_ + tz] - (m + logf(E));
  }
}

__global__ void k_phi_smooth(const float* __restrict__ p, float* __restrict__ o){
  int idx = blockIdx.x*256 + threadIdx.x;   // T*B*K
  int t = idx / (B_*K_);
  float pt = p[idx];
  float v;
  if (t == 0)            v = pt + p[idx + B_*K_];
  else if (t == T_-1)    v = p[idx - B_*K_] + 2.0f*pt;
  else                   v = p[idx - B_*K_] + 2.0f*pt + p[idx + B_*K_];
  o[idx] = v;
}

// ---------------- CRF forward scan + entropy (unchanged)
__global__ __launch_bounds__(1024) void k_crf(
    const float* __restrict__ phi, const float* __restrict__ trans,
    const int* __restrict__ lens, float* __restrict__ alphas,
    float* __restrict__ ent_b){
  __shared__ float sal[K_], sH[K_];
  int tid = threadIdx.x, b = blockIdx.x;
  int i = tid & 31, j = tid >> 5;
  float tr = trans[i*K_ + j];
  int len = lens[b];
  if (tid < K_){
    float a0 = phi[b*K_ + tid];
    sal[tid] = a0; sH[tid] = 0.0f;
    alphas[b*K_ + tid] = a0;
  }
  __syncthreads();
  for (int t = 1; t < T_; t++){
    bool active = (t < len);
    float ai = sal[i], Hi = sH[i];
    float aj = sal[j], Hj = sH[j];
    float s = ai + tr;
    float m = s;
    #pragma unroll
    for (int off=16; off; off>>=1) m = fmaxf(m, __shfl_xor(m, off, 32));
    float e = expf(s - m);
    float E = e;
    #pragma unroll
    for (int off=16; off; off>>=1) E += __shfl_xor(E, off, 32);
    float lZ = m + logf(E);
    float w = e / E;
    float logw = s - lZ;
    float nH = w * (Hi - logw);
    #pragma unroll
    for (int off=16; off; off>>=1) nH += __shfl_xor(nH, off, 32);
    float na = lZ + phi[(size_t)t*B_*K_ + b*K_ + j];
    float outa = active ? na : aj;
    float outH = active ? nH : Hj;
    __syncthreads();
    if (i == 0){
      sal[j] = outa; sH[j] = outH;
      alphas[(size_t)t*B_*K_ + b*K_ + j] = outa;
    }
    __syncthreads();
  }
  if (tid < K_){
    float a = sal[tid];
    float m = a;
    #pragma unroll
    for (int off=16; off; off>>=1) m = fmaxf(m, __shfl_xor(m, off, 32));
    float e = expf(a-m), E = e;
    #pragma unroll
    for (int off=16; off; off>>=1) E += __shfl_xor(E, off, 32);
    float lse = m + logf(E);
    float lp = a - lse;
    float v = expf(lp)*(sH[tid]-lp);
    #pragma unroll
    for (int off=16; off; off>>=1) v += __shfl_xor(v, off, 32);
    if (tid == 0) ent_b[b] = v;
  }
}

// ---------------- backward Gumbel sampler (unchanged)
__global__ void k_sampler(const float* __restrict__ alphas, const float* __restrict__ trans,
                          const float* __restrict__ gum, const int* __restrict__ lens,
                          const float* __restrict__ tau_p,
                          float* __restrict__ y_all, int* __restrict__ z_ids){
  int b = blockIdx.x;
  int lane = threadIdx.x;
  int k = lane & 31;
  float inv_tau = 1.0f / tau_p[0];
  int len = lens[b];
  int nid = 0;
  for (int t = T_-1; t >= 0; t--){
    bool active  = (t < len);
    bool is_last = (t == len-1);
    float a = alphas[(size_t)t*B_*K_ + b*K_ + k];
    float lg = is_last ? a : a + trans[k*K_ + nid];
    float val = (lg + gum[(size_t)t*B_*K_ + b*K_ + k]) * inv_tau;
    float m = val;
    #pragma unroll
    for (int off=16; off; off>>=1) m = fmaxf(m, __shfl_xor(m, off, 32));
    float e = expf(val - m), E = e;
    #pragma unroll
    for (int off=16; off; off>>=1) E += __shfl_xor(E, off, 32);
    float y = active ? e/E : 0.0f;
    if (lane < K_) y_all[(size_t)(b*T_ + t)*K_ + k] = y;
    float bv = val; int bk = k;
    #pragma unroll
    for (int off=16; off; off>>=1){
      float ov = __shfl_xor(bv, off, 32);
      int   ok = __shfl_xor(bk, off, 32);
      if (ov > bv || (ov == bv && ok < bk)){ bv = ov; bk = ok; }
    }
    int ids = active ? bk : 0;
    nid = ids;
    if (lane == 0) z_ids[b*T_ + t] = ids;
  }
}

// ---------------- attention 1: ctx from q1 ----------------
__global__ __launch_bounds__(256) void k_attn1(
    const float* __restrict__ q, const float* __restrict__ memk,
    const float* __restrict__ kv_emb, const int* __restrict__ keys,
    const float* __restrict__ av, float* __restrict__ ctx){
  __shared__ float se[16];
  int r = blockIdx.x, tid = threadIdx.x;
  int b = r / TD_;
  int m = tid >> 4, ds = tid & 15;
  float p = 0.0f;
  #pragma unroll 4
  for (int qq = 0; qq < 16; qq++){
    int dd = ds + qq*16;
    p += d_tanh(q[(size_t)r*256 + dd] + memk[(size_t)(b*M_+m)*256 + dd]) * av[dd];
  }
  #pragma unroll
  for (int off=8; off; off>>=1) p += __shfl_xor(p, off, 16);
  if (ds == 0) se[m] = (keys[b*M_+m] != 0) ? p : -1e9f;
  __syncthreads();
  float mx = -1e30f;
  #pragma unroll
  for (int mm=0;mm<16;mm++) mx = fmaxf(mx, se[mm]);
  float den = 0.0f, ex[16];
  #pragma unroll
  for (int mm=0;mm<16;mm++){ ex[mm] = __expf(se[mm]-mx); den += ex[mm]; }
  float cacc = 0.0f;
  #pragma unroll
  for (int mm=0;mm<16;mm++) cacc += ex[mm]*kv_emb[(size_t)(b*M_+mm)*256 + tid];
  ctx[(size_t)r*256 + tid] = cacc/den;
}

// ---------------- attention 2 + copy + gate ----------------
__global__ __launch_bounds__(256) void k_attn2g(
    const float* __restrict__ q2, const float* __restrict__ dint,
    const float* __restrict__ memk2, const int* __restrict__ keys,
    const float* __restrict__ cv, const float* __restrict__ gW, const float* __restrict__ gb,
    const int* __restrict__ sent, const float* __restrict__ kv_emb,
    float* __restrict__ cpx, float* __restrict__ gsig){
  __shared__ float se2[16];
  __shared__ float sred[4];
  int r = blockIdx.x, tid = threadIdx.x;
  int b = r / TD_, t = r - b*TD_;
  int m = tid >> 4, ds = tid & 15;
  float p = 0.0f;
  #pragma unroll 4
  for (int qq = 0; qq < 16; qq++){
    int dd = ds + qq*16;
    p += d_tanh(q2[(size_t)r*256 + dd] + memk2[(size_t)(b*M_+m)*256 + dd]) * cv[dd];
  }
  #pragma unroll
  for (int off=8; off; off>>=1) p += __shfl_xor(p, off, 16);
  if (ds == 0) se2[m] = (keys[b*M_+m] != 0) ? p : -1e9f;
  float gp = dint[(size_t)r*256 + tid]*gW[tid];
  #pragma unroll
  for (int off=32; off; off>>=1) gp += __shfl_xor(gp, off, 64);
  if ((tid & 63) == 0) sred[tid>>6] = gp;
  __syncthreads();
  if (tid == 0){
    float mx = -1e30f;
    #pragma unroll
    for (int mm=0;mm<16;mm++) mx = fmaxf(mx, se2[mm]);
    float den = 0.0f, ex[16];
    #pragma unroll
    for (int mm=0;mm<16;mm++){ ex[mm] = __expf(se2[mm]-mx); den += ex[mm]; }
    int txi = sent[b*T_ + t + 1];
    float cp = 0.0f;
    #pragma unroll
    for (int mm=0;mm<16;mm++) if (keys[b*M_+mm] == txi) cp += ex[mm]/den;
    cpx[r] = cp;
    gsig[r] = d_sig(sred[0]+sred[1]+sred[2]+sred[3] + gb[0]);
  }
  (void)kv_emb;
}

// ---------------- out_W transpose+bf16: W[256][V] -> Wt[V][256]
__global__ __launch_bounds__(256) void k_wt(const float* __restrict__ W,
                                            unsigned short* __restrict__ Wt){
  __shared__ unsigned short st[64][258];
  int tid = threadIdx.x; int c0 = blockIdx.x*64;
  for (int l = tid; l < 64*256; l += 256){
    int k = l >> 6, c = l & 63;
    st[c][k] = f2bf(W[(size_t)k*V_ + c0 + c]);
  }
  __syncthreads();
  for (int l = tid; l < 64*256; l += 256){
    int c = l >> 8, k = l & 255;
    Wt[(size_t)(c0+c)*256 + k] = st[c][k];
  }
}

// ---------------- MFMA bf16 GEMM + online LSE over V
// grid (127, 32), 512 threads (8 waves), M=128 rows, chunk = 64 cols
__global__ __launch_bounds__(512) void k_lse_mfma(
    const float* __restrict__ Af,           // dec_int fp32 [R][256]
    const unsigned short* __restrict__ Wt,  // [V][256] bf16
    const float* __restrict__ bias,
    float* __restrict__ part){              // [R][32][2]
  __shared__ unsigned short Al[128*256];    // 64KB, XOR-swizzled
  __shared__ unsigned short Wl[64*256];     // 32KB, XOR-swizzled
  int tid = threadIdx.x;
  int row0 = blockIdx.x*128;
  // stage A (fp32 -> bf16, swizzled)
  #pragma unroll
  for (int q = 0; q < 8; q++){
    int u = tid + q*512;
    int row = u >> 5, slot = u & 31;
    const float* src = Af + (size_t)(row0+row)*256 + slot*8;
    union { unsigned short us[8]; uint4 v4; } tu;
    #pragma unroll
    for (int j = 0; j < 8; j++) tu.us[j] = f2bf(src[j]);
    int dst = row*512 + ((slot*16) ^ ((row&7)<<4));
    *reinterpret_cast<uint4*>(reinterpret_cast<char*>(Al) + dst) = tu.v4;
  }
  __syncthreads();
  int w = tid >> 6, l = tid & 63;
  int arow = 16*w + (l & 15);
  short8 afr[8];
  #pragma unroll
  for (int k0 = 0; k0 < 8; k0++){
    int kb = k0*64 + ((l>>4)*16);
    afr[k0] = *reinterpret_cast<const short8*>(
        reinterpret_cast<const char*>(Al) + arow*512 + (kb ^ ((arow&7)<<4)));
  }
  float rm[4] = {-3.0e38f,-3.0e38f,-3.0e38f,-3.0e38f};
  float rs[4] = {0.f,0.f,0.f,0.f};
  for (int ct = blockIdx.y; ct < 500; ct += NCH_){
    int col0 = ct*64;
    __syncthreads();
    #pragma unroll
    for (int q = 0; q < 4; q++){
      int u = tid + q*512;
      int c = u >> 5, slot = u & 31;
      int dst = c*512 + ((slot*16) ^ ((c&7)<<4));
      *reinterpret_cast<uint4*>(reinterpret_cast<char*>(Wl) + dst) =
        *reinterpret_cast<const uint4*>(
            reinterpret_cast<const char*>(Wt) + ((size_t)(col0+c)*256 + slot*8)*2);
    }
    __syncthreads();
    f32x4 acc[4];
    #pragma unroll
    for (int nf=0;nf<4;nf++) acc[nf] = (f32x4){0.f,0.f,0.f,0.f};
    #pragma unroll
    for (int k0 = 0; k0 < 8; k0++){
      int kb = k0*64 + ((l>>4)*16);
      #pragma unroll
      for (int nf = 0; nf < 4; nf++){
        int bc = nf*16 + (l & 15);
        short8 bfr = *reinterpret_cast<const short8*>(
            reinterpret_cast<const char*>(Wl) + bc*512 + (kb ^ ((bc&7)<<4)));
        acc[nf] = __builtin_amdgcn_mfma_f32_16x16x32_bf16(afr[k0], bfr, acc[nf], 0, 0, 0);
      }
    }
    float bb[4];
    #pragma unroll
    for (int nf=0;nf<4;nf++) bb[nf] = bias[col0 + nf*16 + (l&15)];
    #pragma unroll
    for (int r4 = 0; r4 < 4; r4++){
      float v0 = acc[0][r4]+bb[0], v1 = acc[1][r4]+bb[1];
      float v2 = acc[2][r4]+bb[2], v3 = acc[3][r4]+bb[3];
      float tm = fmaxf(fmaxf(v0,v1), fmaxf(v2,v3));
      #pragma unroll
      for (int off=8; off; off>>=1) tm = fmaxf(tm, __shfl_xor(tm, off, 16));
      float ts = __expf(v0-tm)+__expf(v1-tm)+__expf(v2-tm)+__expf(v3-tm);
      #pragma unroll
      for (int off=8; off; off>>=1) ts += __shfl_xor(ts, off, 16);
      float M = fmaxf(rm[r4], tm);
      rs[r4] = rs[r4]*__expf(rm[r4]-M) + ts*__expf(tm-M);
      rm[r4] = M;
    }
  }
  if ((l & 15) == 0){
    #pragma unroll
    for (int r4 = 0; r4 < 4; r4++){
      int grow = row0 + 16*w + (l>>4)*4 + r4;
      part[((size_t)grow*NCH_ + blockIdx.y)*2 + 0] = rm[r4];
      part[((size_t)grow*NCH_ + blockIdx.y)*2 + 1] = rs[r4];
    }
  }
}

__global__ void k_lse_combine(const float* __restrict__ part, float* __restrict__ lse){
  int r = blockIdx.x*256 + threadIdx.x;
  if (r >= R_) return;
  float M = -3.0e38f;
  for (int c = 0; c < NCH_; c++) M = fmaxf(M, part[((size_t)r*NCH_+c)*2]);
  float S = 0.0f;
  for (int c = 0; c < NCH_; c++){
    float m = part[((size_t)r*NCH_+c)*2], s = part[((size_t)r*NCH_+c)*2+1];
    S += s*__expf(m - M);
  }
  lse[r] = M + logf(S);
}

__global__ void k_logit_tx(const float* __restrict__ dint, const float* __restrict__ W,
                           const float* __restrict__ bias, const int* __restrict__ sent,
                           float* __restrict__ out){
  int r = blockIdx.x;
  int b = r / TD_, t = r % TD_;
  int tx = sent[b*T_ + t + 1];
  int lane = threadIdx.x;
  float acc = 0.0f;
  #pragma unroll
  for (int q = 0; q < 4; q++){
    int d = lane + q*64;
    acc += dint[(size_t)r*256 + d]*W[(size_t)d*V_ + tx];
  }
  #pragma unroll
  for (int off=32; off; off>>=1) acc += __shfl_xor(acc, off, 64);
  if (lane == 0) out[r] = acc + bias[tx];
}

__global__ __launch_bounds__(256) void k_final(
    const float* __restrict__ lse, const float* __restrict__ ltx,
    const float* __restrict__ gsig, const float* __restrict__ cpx,
    const float* __restrict__ lpz, const float* __restrict__ ent_b,
    const int* __restrict__ lens, float* __restrict__ out){
  __shared__ float sred[256];
  int tid = threadIdx.x;
  float sum = 0.0f;
  for (int r = tid; r < R_; r += 256){
    int b = r / TD_, t = r % TD_;
    if (t < lens[b]){
      float g = gsig[r];
      float lm = __expf(ltx[r] - lse[r]);
      float p = (1.0f-g)*lm + g*cpx[r] + 1e-10f;
      sum += logf(p) + lpz[r];
    }
  }
  sred[tid] = sum;
  __syncthreads();
  for (int s = 128; s; s >>= 1){ if (tid < s) sred[tid] += sred[tid+s]; __syncthreads(); }
  if (tid == 0){
    float es = 0.0f, dn = 0.0f;
    for (int b = 0; b < B_; b++){ es += ent_b[b]; dn += (float)lens[b]; }
    out[0] = -( es/(float)B_ + sred[0]/dn );
  }
}

} // anonymous namespace

extern "C" void kernel_launch(void* const* d_in, const int* in_sizes, int n_in,
                              void* d_out, int out_size, void* d_ws, size_t ws_size,
                              hipStream_t stream){
  const int*   keys  = (const int*)d_in[0];
  const int*   vals  = (const int*)d_in[1];
  const int*   sent  = (const int*)d_in[2];
  const int*   lens  = (const int*)d_in[3];
  const float* tau   = (const float*)d_in[4];
  const float* xl    = (const float*)d_in[5];
  const float* gum   = (const float*)d_in[6];
  const float* drop  = (const float*)d_in[7];
  const float* emb   = (const float*)d_in[8];
  const float* z_emb = (const float*)d_in[9];
  const float* eWih  = (const float*)d_in[10];
  const float* eWhh  = (const float*)d_in[11];
  const float* eb    = (const float*)d_in[12];
  const float* crfW  = (const float*)d_in[13];
  const float* crfb  = (const float*)d_in[14];
  const float* trans = (const float*)d_in[15];
  const float* iWh   = (const float*)d_in[16];
  const float* ibh   = (const float*)d_in[17];
  const float* iWc   = (const float*)d_in[18];
  const float* ibc   = (const float*)d_in[19];
  const float* dWih  = (const float*)d_in[20];
  const float* dWhh  = (const float*)d_in[21];
  const float* db    = (const float*)d_in[22];
  const float* aWq   = (const float*)d_in[23];
  const float* aWk   = (const float*)d_in[24];
  const float* av    = (const float*)d_in[25];
  const float* aoW   = (const float*)d_in[26];
  const float* aob   = (const float*)d_in[27];
  const float* pzW   = (const float*)d_in[28];
  const float* pzb   = (const float*)d_in[29];
  const float* intW  = (const float*)d_in[30];
  const float* intb  = (const float*)d_in[31];
  const float* outW  = (const float*)d_in[32];
  const float* outb  = (const float*)d_in[33];
  const float* cWq   = (const float*)d_in[34];
  const float* cWk   = (const float*)d_in[35];
  const float* cv    = (const float*)d_in[36];
  const float* gW    = (const float*)d_in[37];
  const float* gb    = (const float*)d_in[38];
  (void)in_sizes; (void)n_in; (void)out_size; (void)ws_size;

  float* ws = (float*)d_ws;
  size_t o = 0;
  auto alloc = [&](size_t n){ size_t r = o; o += (n + 3) & ~(size_t)3; return r; };
  float* sent_emb = ws + alloc((size_t)B_*T_*D_);
  float* kv_emb   = ws + alloc((size_t)B_*M_*D_);
  float* kv_enc   = ws + alloc((size_t)B_*D_);
  float* h0       = ws + alloc((size_t)B_*D_);
  float* c0       = ws + alloc((size_t)B_*D_);
  float* memk     = ws + alloc((size_t)B_*M_*D_);
  float* memk2    = ws + alloc((size_t)B_*M_*D_);
  float* xW       = ws + alloc((size_t)B_*T_*D4_);   // reused enc then dec
  float* encH     = ws + alloc((size_t)B_*T_*D_);    // enc_out; later aliased as Hdec
  float* phi_raw  = ws + alloc((size_t)T_*B_*K_);
  float* phi_sm   = ws + alloc((size_t)T_*B_*K_);
  float* alphas   = ws + alloc((size_t)T_*B_*K_);
  float* ent_b    = ws + alloc((size_t)B_);
  float* y_all    = ws + alloc((size_t)B_*T_*K_);    // later aliased as z_logits
  float* zse      = ws + alloc((size_t)B_*T_*D_);
  float* qbuf     = ws + alloc((size_t)R_*D_);       // q1 then q2
  float* ctx      = ws + alloc((size_t)R_*D_);
  float* dec_out  = ws + alloc((size_t)R_*D_);
  float* dint     = ws + alloc((size_t)R_*D_);
  float* lpz_b    = ws + alloc((size_t)R_);
  float* gsig     = ws + alloc((size_t)R_);
  float* cpx      = ws + alloc((size_t)R_);
  float* ltx      = ws + alloc((size_t)R_);
  float* lse      = ws + alloc((size_t)R_);
  float* part     = ws + alloc((size_t)R_*NCH_*2);
  int*   z_ids    = (int*)(ws + alloc((size_t)B_*T_));
  unsigned short* Wtbf = (unsigned short*)(ws + alloc((size_t)V_*D_/2));

  float* Hdec  = encH;   // alias: enc_out dead after k_phi
  float* zlbuf = y_all;  // alias: y_all dead after zse gemm

  // prep
  k_sent_emb<<<B_*T_*D_/256, 256, 0, stream>>>(sent, emb, sent_emb);
  k_kv_emb  <<<B_*M_*D_/256, 256, 0, stream>>>(keys, vals, emb, kv_emb);
  k_kv_enc  <<<B_*D_/256, 256, 0, stream>>>(keys, kv_emb, kv_enc);
  k_rowgemm <<<B_,     256, 0, stream>>>(kv_enc, iWh, ibh, h0, 256, 256);
  k_rowgemm <<<B_,     256, 0, stream>>>(kv_enc, iWc, ibc, c0, 256, 256);
  k_rowgemm <<<B_*M_,  256, 0, stream>>>(kv_emb, aWk, nullptr, memk, 256, 256);
  k_rowgemm <<<B_*M_,  256, 0, stream>>>(kv_emb, cWk, nullptr, memk2, 256, 256);
  k_wt      <<<V_/64, 256, 0, stream>>>(outW, Wtbf);

  // encoder
  k_tile_gemm<256,0><<<dim3(B_*T_/64, D4_/64), 256, 0, stream>>>(
      sent_emb, nullptr, eWih, eb, xW, D4_, nullptr, nullptr);
  k_lstm_scan<<<B_/2, 512, 0, stream>>>(xW, eWhh, nullptr, nullptr, encH, T_);
  k_phi<<<B_*T_/8, 256, 0, stream>>>(encH, crfW, crfb, phi_raw);
  k_phi_smooth<<<T_*B_*K_/256, 256, 0, stream>>>(phi_raw, phi_sm);
  k_crf<<<B_, 1024, 0, stream>>>(phi_sm, trans, lens, alphas, ent_b);
  k_sampler<<<B_, 64, 0, stream>>>(alphas, trans, gum, lens, tau, y_all, z_ids);
  k_rowgemm<<<B_*T_, 256, 0, stream>>>(y_all, z_emb, nullptr, zse, K_, 256);

  // decoder inputs + scan
  k_tile_gemm<256,1><<<dim3(R_/64, D4_/64), 256, 0, stream>>>(
      sent_emb, zse, dWih, db, xW, D4_, drop, xl);
  k_lstm_scan<<<B_/2, 512, 0, stream>>>(xW, dWhh, h0, c0, Hdec, TD_);

  // decoder post-processing (fully parallel over R rows)
  k_tile_gemm<256,0><<<dim3(R_/64, D_/64), 256, 0, stream>>>(
      Hdec, nullptr, aWq, nullptr, qbuf, D_, nullptr, nullptr);
  k_attn1<<<R_, 256, 0, stream>>>(qbuf, memk, kv_emb, keys, av, ctx);
  k_tile_gemm<512,2><<<dim3(R_/64, D_/64), 256, 0, stream>>>(
      Hdec, ctx, aoW, aob, dec_out, D_, nullptr, nullptr);
  k_zl<<<R_/8, 256, 0, stream>>>(dec_out, pzW, pzb, zlbuf);
  k_lpz<<<R_, 64, 0, stream>>>(zlbuf, z_ids, lpz_b);
  k_tile_gemm<512,3><<<dim3(R_/64, D_/64), 256, 0, stream>>>(
      dec_out, zse, intW, intb, dint, D_, nullptr, nullptr);
  k_tile_gemm<256,0><<<dim3(R_/64, D_/64), 256, 0, stream>>>(
      dint, nullptr, cWq, nullptr, qbuf, D_, nullptr, nullptr);
  k_attn2g<<<R_, 256, 0, stream>>>(qbuf, dint, memk2, keys, cv, gW, gb, sent, kv_emb,
                                   cpx, gsig);

  // vocab LSE (bf16 MFMA) + target logit + loss
  k_lse_mfma<<<dim3(R_/128, NCH_), 512, 0, stream>>>(dint, Wtbf, outb, part);
  k_lse_combine<<<(R_+255)/256, 256, 0, stream>>>(part, lse);
  k_logit_tx<<<R_, 64, 0, stream>>>(dint, outW, outb, sent, ltx);
  k_final<<<1, 256, 0, stream>>>(lse, ltx, gsig, cpx, lpz_b, ent_b, lens, (float*)d_out);
}